// Round 7
// baseline (302.254 us; speedup 1.0000x reference)
//
#include <hip/hip_runtime.h>
#include <hip/hip_bf16.h>
#include <math.h>

#define B_SZ   2
#define S_LEN  2048
#define C_DIM  1280
#define H_NUM  20
#define D_HEAD 64
#define M_TOT  (B_SZ * S_LEN)          // 4096

typedef __bf16 bf16;
typedef __bf16 bf16x8 __attribute__((ext_vector_type(8)));
typedef __bf16 bf16x4 __attribute__((ext_vector_type(4)));
typedef float  f32x4  __attribute__((ext_vector_type(4)));

__device__ inline f32x4 zero4() { f32x4 z; z[0]=z[1]=z[2]=z[3]=0.f; return z; }

// async global->LDS, 16B per lane. LDS dest must be wave-uniform base + lane*16.
__device__ __forceinline__ void async_copy16(void* lds, const void* g) {
    __builtin_amdgcn_global_load_lds(
        (const __attribute__((address_space(1))) unsigned int*)g,
        (__attribute__((address_space(3))) unsigned int*)lds,
        16, 0, 0);
}

// ---------------- hs fp32 -> bf16 ----------------
__global__ __launch_bounds__(256) void k_convert_hs(const float* __restrict__ in,
                                                    bf16* __restrict__ out) {
    int i = (blockIdx.x * 256 + threadIdx.x) * 4;
    float4 v = *(const float4*)(in + i);
    bf16x4 o; o[0]=(bf16)v.x; o[1]=(bf16)v.y; o[2]=(bf16)v.z; o[3]=(bf16)v.w;
    *(bf16x4*)(out + i) = o;
}

// ------------- W fp32 [K][N] -> bf16 WT [N][K] -------------
__global__ __launch_bounds__(256) void k_transpose_w(
    const float* __restrict__ w0, const float* __restrict__ w1,
    const float* __restrict__ w2, const float* __restrict__ w3,
    bf16* __restrict__ o0, bf16* __restrict__ o1,
    bf16* __restrict__ o2, bf16* __restrict__ o3) {
    __shared__ float t[32][33];
    const float* w = blockIdx.z==0 ? w0 : blockIdx.z==1 ? w1 : blockIdx.z==2 ? w2 : w3;
    bf16*       o  = blockIdx.z==0 ? o0 : blockIdx.z==1 ? o1 : blockIdx.z==2 ? o2 : o3;
    int k0 = blockIdx.y*32, n0 = blockIdx.x*32;
    int tx = threadIdx.x & 31, ty = threadIdx.x >> 5;   // 32 x 8
    #pragma unroll
    for (int i = 0; i < 32; i += 8)
        t[ty+i][tx] = w[(size_t)(k0+ty+i)*C_DIM + n0 + tx];
    __syncthreads();
    #pragma unroll
    for (int i = 0; i < 32; i += 8)
        o[(size_t)(n0+ty+i)*C_DIM + k0 + tx] = (bf16)t[tx][ty+i];
}

// ------------- QKV GEMM: [4096x1280] @ [1280x1280] -> Q/K/V [B,H,S,D] bf16 -------------
#define BM 128
#define BN 128
#define BK 32
__global__ __launch_bounds__(256) void k_gemm_qkv(
    const bf16* __restrict__ A,                      // hs_bf [4096][1280]
    const bf16* __restrict__ WqT, const bf16* __restrict__ WkT, const bf16* __restrict__ WvT,
    bf16* __restrict__ Qo, bf16* __restrict__ Ko, bf16* __restrict__ Vo) {
    __shared__ bf16 Al[BM][BK];
    __shared__ bf16 Bl[BN][BK];
    const int z = blockIdx.z;
    const bf16* BT = z==0 ? WqT : z==1 ? WkT : WvT;
    bf16* Out      = z==0 ? Qo  : z==1 ? Ko  : Vo;
    const float scale = (z==0) ? 0.125f : 1.0f;      // fold 1/sqrt(D) into Q
    const int m0 = blockIdx.y * BM, n0 = blockIdx.x * BN;
    const int tid = threadIdx.x, lane = tid & 63, wid = tid >> 6;
    const int wm = wid >> 1, wn = wid & 1;
    const int g = lane >> 4, lr = lane & 15;
    f32x4 acc[4][4];
    #pragma unroll
    for (int i=0;i<4;i++)
        #pragma unroll
        for (int j=0;j<4;j++)
            acc[i][j] = zero4();
    const int srow = tid >> 2, scol = (tid & 3) * 8;
    for (int k0 = 0; k0 < C_DIM; k0 += BK) {
        async_copy16(&Al[srow][scol],    &A [(size_t)(m0+srow)*C_DIM    + k0 + scol]);
        async_copy16(&Al[srow+64][scol], &A [(size_t)(m0+srow+64)*C_DIM + k0 + scol]);
        async_copy16(&Bl[srow][scol],    &BT[(size_t)(n0+srow)*C_DIM    + k0 + scol]);
        async_copy16(&Bl[srow+64][scol], &BT[(size_t)(n0+srow+64)*C_DIM + k0 + scol]);
        __syncthreads();
        bf16x8 af[4], bfr[4];
        #pragma unroll
        for (int mf=0;mf<4;mf++) af[mf]  = *(const bf16x8*)&Al[wm*64+mf*16+lr][g*8];
        #pragma unroll
        for (int nf=0;nf<4;nf++) bfr[nf] = *(const bf16x8*)&Bl[wn*64+nf*16+lr][g*8];
        #pragma unroll
        for (int mf=0;mf<4;mf++)
            #pragma unroll
            for (int nf=0;nf<4;nf++)
                acc[mf][nf] = __builtin_amdgcn_mfma_f32_16x16x32_bf16(af[mf], bfr[nf], acc[mf][nf], 0,0,0);
        __syncthreads();
    }
    #pragma unroll
    for (int mf=0;mf<4;mf++) {
        #pragma unroll
        for (int nf=0;nf<4;nf++) {
            int n = n0 + wn*64 + nf*16 + lr;
            int h = n >> 6, d = n & 63;
            #pragma unroll
            for (int r=0;r<4;r++) {
                int m = m0 + wm*64 + mf*16 + g*4 + r;
                int b = m >> 11, s = m & (S_LEN-1);
                Out[(size_t)((b*H_NUM + h)*S_LEN + s)*D_HEAD + d] = (bf16)(acc[mf][nf][r] * scale);
            }
        }
    }
}

// ------------- output GEMM with bias+residual epilogue, fp32 out -------------
__global__ __launch_bounds__(256) void k_gemm_out(
    const bf16* __restrict__ A,                     // Oattn [4096][1280]
    const bf16* __restrict__ WoT,
    const float* __restrict__ bo,
    const float* __restrict__ res,                  // hidden_states fp32
    float* __restrict__ out) {
    __shared__ bf16 Al[BM][BK];
    __shared__ bf16 Bl[BN][BK];
    const int m0 = blockIdx.y * BM, n0 = blockIdx.x * BN;
    const int tid = threadIdx.x, lane = tid & 63, wid = tid >> 6;
    const int wm = wid >> 1, wn = wid & 1;
    const int g = lane >> 4, lr = lane & 15;
    f32x4 acc[4][4];
    #pragma unroll
    for (int i=0;i<4;i++)
        #pragma unroll
        for (int j=0;j<4;j++)
            acc[i][j] = zero4();
    const int srow = tid >> 2, scol = (tid & 3) * 8;
    for (int k0 = 0; k0 < C_DIM; k0 += BK) {
        async_copy16(&Al[srow][scol],    &A  [(size_t)(m0+srow)*C_DIM    + k0 + scol]);
        async_copy16(&Al[srow+64][scol], &A  [(size_t)(m0+srow+64)*C_DIM + k0 + scol]);
        async_copy16(&Bl[srow][scol],    &WoT[(size_t)(n0+srow)*C_DIM    + k0 + scol]);
        async_copy16(&Bl[srow+64][scol], &WoT[(size_t)(n0+srow+64)*C_DIM + k0 + scol]);
        __syncthreads();
        bf16x8 af[4], bfr[4];
        #pragma unroll
        for (int mf=0;mf<4;mf++) af[mf]  = *(const bf16x8*)&Al[wm*64+mf*16+lr][g*8];
        #pragma unroll
        for (int nf=0;nf<4;nf++) bfr[nf] = *(const bf16x8*)&Bl[wn*64+nf*16+lr][g*8];
        #pragma unroll
        for (int mf=0;mf<4;mf++)
            #pragma unroll
            for (int nf=0;nf<4;nf++)
                acc[mf][nf] = __builtin_amdgcn_mfma_f32_16x16x32_bf16(af[mf], bfr[nf], acc[mf][nf], 0,0,0);
        __syncthreads();
    }
    #pragma unroll
    for (int mf=0;mf<4;mf++) {
        #pragma unroll
        for (int nf=0;nf<4;nf++) {
            int n = n0 + wn*64 + nf*16 + lr;
            float bias = bo[n];
            #pragma unroll
            for (int r=0;r<4;r++) {
                int m = m0 + wm*64 + mf*16 + g*4 + r;
                size_t idx = (size_t)m*C_DIM + n;
                out[idx] = acc[mf][nf][r] + bias + res[idx];
            }
        }
    }
}

// ------------- V [B,H,S,D] -> VT [B,H,D,S] -------------
__global__ __launch_bounds__(256) void k_transpose_v(const bf16* __restrict__ V,
                                                     bf16* __restrict__ VT) {
    __shared__ bf16 t[64][72];
    int bh = blockIdx.x >> 5;
    int s0 = (blockIdx.x & 31) * 64;
    int tid = threadIdx.x;
    #pragma unroll
    for (int p = 0; p < 2; p++) {
        int e = tid + p*256;
        int row = e >> 3, col = (e & 7) * 8;
        *(bf16x8*)&t[row][col] = *(const bf16x8*)&V[(size_t)(bh*S_LEN + s0 + row)*D_HEAD + col];
    }
    __syncthreads();
    #pragma unroll
    for (int p = 0; p < 2; p++) {
        int e = tid + p*256;
        int d = e >> 3, sc = (e & 7) * 8;
        bf16x8 v;
        #pragma unroll
        for (int j = 0; j < 8; j++) v[j] = t[sc+j][d];
        *(bf16x8*)&VT[(size_t)(bh*D_HEAD + d)*S_LEN + s0 + sc] = v;
    }
}

// ------------- flash attention + loss partials -------------
// 4 waves x 32 q-rows = 128 q/block. K/V read DIRECTLY from global (L1/L2-
// resident: 256KB per head per tensor; all 4 waves read identical lines).
// No __syncthreads in the main loop (Pl is per-wave) -> waves drift freely.
// Unnormalized softmax (scores ~N(0,1)), lane-local l/sum(p^2).
// XCD swizzle: 640 blocks = 8 XCDs x 80 contiguous; the 16 q-blocks of a
// head land on one XCD -> K/V served from that XCD's L2 (2.5MB < 4MB).
#define KVB 64
__global__ __launch_bounds__(256) void k_attn(
    const bf16* __restrict__ Q,    // [B,H,S,D], pre-scaled by 1/8
    const bf16* __restrict__ Kg,   // [B,H,S,D]
    const bf16* __restrict__ VT,   // [B,H,D,S]
    bf16* __restrict__ O,          // [B,S,H,D]
    float* __restrict__ lossPart) {
    __shared__ bf16 Pl[4][32][68];     // stride 136B: conflict-free scalar writes
    __shared__ float wred[4];

    const int id  = blockIdx.x;        // 0..639
    const int fid = (id & 7) * 80 + (id >> 3);   // XCD-contiguous remap (640%8==0)
    const int bh = fid >> 4;           // 0..39
    const int qb = fid & 15;           // 0..15
    const int b = bh / H_NUM, hh = bh % H_NUM;
    const int tid = threadIdx.x, lane = tid & 63, wid = tid >> 6;
    const int g = lane >> 4, lr = lane & 15;

    const bf16* Kbase = Kg + (size_t)bh * S_LEN * D_HEAD;
    const bf16* Vbase = VT + (size_t)bh * D_HEAD * S_LEN;

    // Q fragments: 2 strips x 2 k-parts, in registers
    bf16x8 aq[2][2];
    #pragma unroll
    for (int h=0; h<2; ++h) {
        int row = qb*128 + wid*32 + h*16 + lr;
        const bf16* qp = Q + ((size_t)bh*S_LEN + row)*D_HEAD;
        aq[h][0] = *(const bf16x8*)(qp + g*8);
        aq[h][1] = *(const bf16x8*)(qp + 32 + g*8);
    }

    f32x4 o_acc[2][4];
    float l_part[2][4], s2_part[2][4];
    #pragma unroll
    for (int h=0;h<2;++h) {
        #pragma unroll
        for (int i=0;i<4;i++) { o_acc[h][i] = zero4(); l_part[h][i]=0.f; s2_part[h][i]=0.f; }
    }

    for (int kv0 = 0; kv0 < S_LEN; kv0 += KVB) {
        // QK^T: K fragments straight from global; shared by both q-strips
        f32x4 sf[2][4];
        #pragma unroll
        for (int nf=0; nf<4; ++nf) {
            const bf16* krow = Kbase + (size_t)(kv0 + nf*16 + lr) * D_HEAD;
            bf16x8 bk0 = *(const bf16x8*)(krow + g*8);
            bf16x8 bk1 = *(const bf16x8*)(krow + 32 + g*8);
            #pragma unroll
            for (int h=0;h<2;++h) {
                f32x4 c = zero4();
                c = __builtin_amdgcn_mfma_f32_16x16x32_bf16(aq[h][0], bk0, c, 0,0,0);
                c = __builtin_amdgcn_mfma_f32_16x16x32_bf16(aq[h][1], bk1, c, 0,0,0);
                sf[h][nf] = c;
            }
        }
        // unnormalized p = exp(s): lane-local accumulation, conflict-free P writes
        #pragma unroll
        for (int h=0;h<2;++h)
            #pragma unroll
            for (int nf=0;nf<4;++nf)
                #pragma unroll
                for (int r=0;r<4;++r) {
                    float p = __expf(sf[h][nf][r]);
                    l_part[h][r]  += p;
                    s2_part[h][r] += p*p;
                    Pl[wid][h*16 + g*4 + r][nf*16 + lr] = (bf16)p;
                }
        __threadfence_block();
        // P fragments (A-operand), loaded once, reused across all nf
        bf16x8 ap[2][2];
        #pragma unroll
        for (int h=0;h<2;++h) {
            const bf16* prow = &Pl[wid][h*16 + lr][0];
            bf16x4 lo0 = *(const bf16x4*)(prow + g*8);
            bf16x4 hi0 = *(const bf16x4*)(prow + g*8 + 4);
            bf16x4 lo1 = *(const bf16x4*)(prow + 32 + g*8);
            bf16x4 hi1 = *(const bf16x4*)(prow + 32 + g*8 + 4);
            ap[h][0] = __builtin_shufflevector(lo0, hi0, 0,1,2,3,4,5,6,7);
            ap[h][1] = __builtin_shufflevector(lo1, hi1, 0,1,2,3,4,5,6,7);
        }
        // PV: V fragments straight from global; shared by both q-strips
        #pragma unroll
        for (int nf=0;nf<4;++nf) {
            const bf16* vrow = Vbase + (size_t)(nf*16 + lr) * S_LEN + kv0;
            bf16x8 bv0 = *(const bf16x8*)(vrow + g*8);
            bf16x8 bv1 = *(const bf16x8*)(vrow + 32 + g*8);
            #pragma unroll
            for (int h=0;h<2;++h) {
                o_acc[h][nf] = __builtin_amdgcn_mfma_f32_16x16x32_bf16(ap[h][0], bv0, o_acc[h][nf], 0,0,0);
                o_acc[h][nf] = __builtin_amdgcn_mfma_f32_16x16x32_bf16(ap[h][1], bv1, o_acc[h][nf], 0,0,0);
            }
        }
        // no block barrier: Pl is per-wave, K/V come from cache
    }

    // final cross-lane reduce of l and s2 over the 16-lane lr group
    #pragma unroll
    for (int h=0;h<2;++h)
        #pragma unroll
        for (int r=0;r<4;++r)
            #pragma unroll
            for (int msk=1; msk<16; msk<<=1) {
                l_part[h][r]  += __shfl_xor(l_part[h][r], msk);
                s2_part[h][r] += __shfl_xor(s2_part[h][r], msk);
            }
    // O write
    #pragma unroll
    for (int h=0;h<2;++h)
        #pragma unroll
        for (int nf=0;nf<4;++nf) {
            int d = nf*16 + lr;
            #pragma unroll
            for (int r=0;r<4;++r) {
                int s = qb*128 + wid*32 + h*16 + g*4 + r;
                O[(size_t)((b*S_LEN + s)*H_NUM + hh)*D_HEAD + d] = (bf16)(o_acc[h][nf][r] / l_part[h][r]);
            }
        }
    // loss partial: sum over rows of s2/l^2 (each row replicated 16x -> /16)
    float v = 0.f;
    #pragma unroll
    for (int h=0;h<2;++h)
        #pragma unroll
        for (int r=0;r<4;++r) v += s2_part[h][r] / (l_part[h][r]*l_part[h][r]);
    #pragma unroll
    for (int msk=1; msk<64; msk<<=1) v += __shfl_xor(v, msk);
    v *= (1.0f/16.0f);
    if (lane == 0) wred[wid] = v;
    __syncthreads();
    if (tid == 0) lossPart[fid] = wred[0]+wred[1]+wred[2]+wred[3];
}

// ------------- deterministic loss reduce -------------
__global__ __launch_bounds__(256) void k_loss(const float* __restrict__ part,
                                              float* __restrict__ out, int n) {
    __shared__ float w[4];
    float s = 0.f;
    for (int i = threadIdx.x; i < n; i += 256) s += part[i];
    #pragma unroll
    for (int msk=1; msk<64; msk<<=1) s += __shfl_xor(s, msk);
    int lane = threadIdx.x & 63, wid = threadIdx.x >> 6;
    if (lane==0) w[wid] = s;
    __syncthreads();
    if (threadIdx.x==0) out[(size_t)M_TOT*C_DIM] = sqrtf(w[0]+w[1]+w[2]+w[3]);
}

extern "C" void kernel_launch(void* const* d_in, const int* in_sizes, int n_in,
                              void* d_out, int out_size, void* d_ws, size_t ws_size,
                              hipStream_t stream) {
    (void)in_sizes; (void)n_in; (void)out_size; (void)ws_size;
    const float* hs = (const float*)d_in[0];
    const float* Wq = (const float*)d_in[1];
    const float* Wk = (const float*)d_in[2];
    const float* Wv = (const float*)d_in[3];
    const float* Wo = (const float*)d_in[4];
    const float* bo = (const float*)d_in[5];
    float* out = (float*)d_out;

    constexpr size_t HS_E = (size_t)M_TOT * C_DIM;       // 5,242,880
    constexpr size_t W_E  = (size_t)C_DIM * C_DIM;       // 1,638,400
    char* ws = (char*)d_ws;
    size_t off = 0;
    bf16* hs_bf = (bf16*)(ws + off); off += HS_E * 2;
    bf16* WqT   = (bf16*)(ws + off); off += W_E * 2;
    bf16* WkT   = (bf16*)(ws + off); off += W_E * 2;
    bf16* WvT   = (bf16*)(ws + off); off += W_E * 2;
    bf16* WoT   = (bf16*)(ws + off); off += W_E * 2;
    bf16* Qb    = (bf16*)(ws + off); off += HS_E * 2;
    bf16* Kb    = (bf16*)(ws + off); off += HS_E * 2;
    bf16* Vb    = (bf16*)(ws + off); off += HS_E * 2;
    bf16* Ob    = (bf16*)(ws + off); off += HS_E * 2;
    float* lossPart = (float*)(ws + off); off += 640 * 4;
    bf16* VTb = hs_bf;   // reuse hs_bf space after QKV GEMMs

    k_convert_hs<<<HS_E/(256*4), 256, 0, stream>>>(hs, hs_bf);
    k_transpose_w<<<dim3(C_DIM/32, C_DIM/32, 4), 256, 0, stream>>>(Wq, Wk, Wv, Wo, WqT, WkT, WvT, WoT);
    k_gemm_qkv<<<dim3(C_DIM/BN, M_TOT/BM, 3), 256, 0, stream>>>(hs_bf, WqT, WkT, WvT, Qb, Kb, Vb);
    k_transpose_v<<<B_SZ*H_NUM*(S_LEN/64), 256, 0, stream>>>(Vb, VTb);
    k_attn<<<640, 256, 0, stream>>>(Qb, Kb, VTb, Ob, lossPart);
    k_gemm_out<<<dim3(C_DIM/BN, M_TOT/BM), 256, 0, stream>>>(Ob, WoT, bo, hs, out);
    k_loss<<<1, 256, 0, stream>>>(lossPart, out, B_SZ*H_NUM*(S_LEN/128));
}

// Round 8
// 210.618 us; speedup vs baseline: 1.4351x; 1.4351x over previous
//
#include <hip/hip_runtime.h>
#include <hip/hip_bf16.h>
#include <math.h>

#define B_SZ   2
#define S_LEN  2048
#define C_DIM  1280
#define H_NUM  20
#define D_HEAD 64
#define M_TOT  (B_SZ * S_LEN)          // 4096

typedef __bf16 bf16;
typedef __bf16 bf16x8 __attribute__((ext_vector_type(8)));
typedef __bf16 bf16x4 __attribute__((ext_vector_type(4)));
typedef float  f32x4  __attribute__((ext_vector_type(4)));

__device__ inline f32x4 zero4() { f32x4 z; z[0]=z[1]=z[2]=z[3]=0.f; return z; }

// async global->LDS, 16B per lane. LDS dest must be wave-uniform base + lane*16.
__device__ __forceinline__ void async_copy16(void* lds, const void* g) {
    __builtin_amdgcn_global_load_lds(
        (const __attribute__((address_space(1))) unsigned int*)g,
        (__attribute__((address_space(3))) unsigned int*)lds,
        16, 0, 0);
}

// ---------------- hs fp32 -> bf16 ----------------
__global__ __launch_bounds__(256) void k_convert_hs(const float* __restrict__ in,
                                                    bf16* __restrict__ out) {
    int i = (blockIdx.x * 256 + threadIdx.x) * 4;
    float4 v = *(const float4*)(in + i);
    bf16x4 o; o[0]=(bf16)v.x; o[1]=(bf16)v.y; o[2]=(bf16)v.z; o[3]=(bf16)v.w;
    *(bf16x4*)(out + i) = o;
}

// ------------- W fp32 [K][N] -> bf16 WT [N][K] -------------
__global__ __launch_bounds__(256) void k_transpose_w(
    const float* __restrict__ w0, const float* __restrict__ w1,
    const float* __restrict__ w2, const float* __restrict__ w3,
    bf16* __restrict__ o0, bf16* __restrict__ o1,
    bf16* __restrict__ o2, bf16* __restrict__ o3) {
    __shared__ float t[32][33];
    const float* w = blockIdx.z==0 ? w0 : blockIdx.z==1 ? w1 : blockIdx.z==2 ? w2 : w3;
    bf16*       o  = blockIdx.z==0 ? o0 : blockIdx.z==1 ? o1 : blockIdx.z==2 ? o2 : o3;
    int k0 = blockIdx.y*32, n0 = blockIdx.x*32;
    int tx = threadIdx.x & 31, ty = threadIdx.x >> 5;   // 32 x 8
    #pragma unroll
    for (int i = 0; i < 32; i += 8)
        t[ty+i][tx] = w[(size_t)(k0+ty+i)*C_DIM + n0 + tx];
    __syncthreads();
    #pragma unroll
    for (int i = 0; i < 32; i += 8)
        o[(size_t)(n0+ty+i)*C_DIM + k0 + tx] = (bf16)t[tx][ty+i];
}

// ------------- QKV GEMM: [4096x1280] @ [1280x1280] -> Q/K/V [B,H,S,D] bf16 -------------
#define BM 128
#define BN 128
#define BK 32
__global__ __launch_bounds__(256) void k_gemm_qkv(
    const bf16* __restrict__ A,                      // hs_bf [4096][1280]
    const bf16* __restrict__ WqT, const bf16* __restrict__ WkT, const bf16* __restrict__ WvT,
    bf16* __restrict__ Qo, bf16* __restrict__ Ko, bf16* __restrict__ Vo) {
    __shared__ bf16 Al[BM][BK];
    __shared__ bf16 Bl[BN][BK];
    const int z = blockIdx.z;
    const bf16* BT = z==0 ? WqT : z==1 ? WkT : WvT;
    bf16* Out      = z==0 ? Qo  : z==1 ? Ko  : Vo;
    const float scale = (z==0) ? 0.125f : 1.0f;      // fold 1/sqrt(D) into Q
    const int m0 = blockIdx.y * BM, n0 = blockIdx.x * BN;
    const int tid = threadIdx.x, lane = tid & 63, wid = tid >> 6;
    const int wm = wid >> 1, wn = wid & 1;
    const int g = lane >> 4, lr = lane & 15;
    f32x4 acc[4][4];
    #pragma unroll
    for (int i=0;i<4;i++)
        #pragma unroll
        for (int j=0;j<4;j++)
            acc[i][j] = zero4();
    const int srow = tid >> 2, scol = (tid & 3) * 8;
    for (int k0 = 0; k0 < C_DIM; k0 += BK) {
        async_copy16(&Al[srow][scol],    &A [(size_t)(m0+srow)*C_DIM    + k0 + scol]);
        async_copy16(&Al[srow+64][scol], &A [(size_t)(m0+srow+64)*C_DIM + k0 + scol]);
        async_copy16(&Bl[srow][scol],    &BT[(size_t)(n0+srow)*C_DIM    + k0 + scol]);
        async_copy16(&Bl[srow+64][scol], &BT[(size_t)(n0+srow+64)*C_DIM + k0 + scol]);
        __syncthreads();
        bf16x8 af[4], bfr[4];
        #pragma unroll
        for (int mf=0;mf<4;mf++) af[mf]  = *(const bf16x8*)&Al[wm*64+mf*16+lr][g*8];
        #pragma unroll
        for (int nf=0;nf<4;nf++) bfr[nf] = *(const bf16x8*)&Bl[wn*64+nf*16+lr][g*8];
        #pragma unroll
        for (int mf=0;mf<4;mf++)
            #pragma unroll
            for (int nf=0;nf<4;nf++)
                acc[mf][nf] = __builtin_amdgcn_mfma_f32_16x16x32_bf16(af[mf], bfr[nf], acc[mf][nf], 0,0,0);
        __syncthreads();
    }
    #pragma unroll
    for (int mf=0;mf<4;mf++) {
        #pragma unroll
        for (int nf=0;nf<4;nf++) {
            int n = n0 + wn*64 + nf*16 + lr;
            int h = n >> 6, d = n & 63;
            #pragma unroll
            for (int r=0;r<4;r++) {
                int m = m0 + wm*64 + mf*16 + g*4 + r;
                int b = m >> 11, s = m & (S_LEN-1);
                Out[(size_t)((b*H_NUM + h)*S_LEN + s)*D_HEAD + d] = (bf16)(acc[mf][nf][r] * scale);
            }
        }
    }
}

// ------------- output GEMM with bias+residual epilogue, fp32 out -------------
__global__ __launch_bounds__(256) void k_gemm_out(
    const bf16* __restrict__ A,                     // Oattn [4096][1280]
    const bf16* __restrict__ WoT,
    const float* __restrict__ bo,
    const float* __restrict__ res,                  // hidden_states fp32
    float* __restrict__ out) {
    __shared__ bf16 Al[BM][BK];
    __shared__ bf16 Bl[BN][BK];
    const int m0 = blockIdx.y * BM, n0 = blockIdx.x * BN;
    const int tid = threadIdx.x, lane = tid & 63, wid = tid >> 6;
    const int wm = wid >> 1, wn = wid & 1;
    const int g = lane >> 4, lr = lane & 15;
    f32x4 acc[4][4];
    #pragma unroll
    for (int i=0;i<4;i++)
        #pragma unroll
        for (int j=0;j<4;j++)
            acc[i][j] = zero4();
    const int srow = tid >> 2, scol = (tid & 3) * 8;
    for (int k0 = 0; k0 < C_DIM; k0 += BK) {
        async_copy16(&Al[srow][scol],    &A  [(size_t)(m0+srow)*C_DIM    + k0 + scol]);
        async_copy16(&Al[srow+64][scol], &A  [(size_t)(m0+srow+64)*C_DIM + k0 + scol]);
        async_copy16(&Bl[srow][scol],    &WoT[(size_t)(n0+srow)*C_DIM    + k0 + scol]);
        async_copy16(&Bl[srow+64][scol], &WoT[(size_t)(n0+srow+64)*C_DIM + k0 + scol]);
        __syncthreads();
        bf16x8 af[4], bfr[4];
        #pragma unroll
        for (int mf=0;mf<4;mf++) af[mf]  = *(const bf16x8*)&Al[wm*64+mf*16+lr][g*8];
        #pragma unroll
        for (int nf=0;nf<4;nf++) bfr[nf] = *(const bf16x8*)&Bl[wn*64+nf*16+lr][g*8];
        #pragma unroll
        for (int mf=0;mf<4;mf++)
            #pragma unroll
            for (int nf=0;nf<4;nf++)
                acc[mf][nf] = __builtin_amdgcn_mfma_f32_16x16x32_bf16(af[mf], bfr[nf], acc[mf][nf], 0,0,0);
        __syncthreads();
    }
    #pragma unroll
    for (int mf=0;mf<4;mf++) {
        #pragma unroll
        for (int nf=0;nf<4;nf++) {
            int n = n0 + wn*64 + nf*16 + lr;
            float bias = bo[n];
            #pragma unroll
            for (int r=0;r<4;r++) {
                int m = m0 + wm*64 + mf*16 + g*4 + r;
                size_t idx = (size_t)m*C_DIM + n;
                out[idx] = acc[mf][nf][r] + bias + res[idx];
            }
        }
    }
}

// ------------- V [B,H,S,D] -> VT [B,H,D,S] -------------
__global__ __launch_bounds__(256) void k_transpose_v(const bf16* __restrict__ V,
                                                     bf16* __restrict__ VT) {
    __shared__ bf16 t[64][72];
    int bh = blockIdx.x >> 5;
    int s0 = (blockIdx.x & 31) * 64;
    int tid = threadIdx.x;
    #pragma unroll
    for (int p = 0; p < 2; p++) {
        int e = tid + p*256;
        int row = e >> 3, col = (e & 7) * 8;
        *(bf16x8*)&t[row][col] = *(const bf16x8*)&V[(size_t)(bh*S_LEN + s0 + row)*D_HEAD + col];
    }
    __syncthreads();
    #pragma unroll
    for (int p = 0; p < 2; p++) {
        int e = tid + p*256;
        int d = e >> 3, sc = (e & 7) * 8;
        bf16x8 v;
        #pragma unroll
        for (int j = 0; j < 8; j++) v[j] = t[sc+j][d];
        *(bf16x8*)&VT[(size_t)(bh*D_HEAD + d)*S_LEN + s0 + sc] = v;
    }
}

// ------------- flash attention + loss partials -------------
// Swapped-operand flash attn: QK^T computed as mfma(A=K, B=Q^T) -> S^T with
// lane owning col q=lr, rows kv. Physical-kv permutation phys(u,m) =
// (m>>2)*8 + u*4 + (m&3) makes each lane's 8 exp values exactly the PV
// B-fragment k-slice (kv = g*8..g*8+7): P stays in registers, l/sum(p^2)
// are lane-local scalars. PV = mfma(A=V^T, B=P^T) -> O^T.
// K staged to LDS with row bit2<->bit3 swap + XOR granule swizzle; V with
// plain XOR swizzle (both <=2-way conflict = free). 1 barrier/tile, dbuf.
#define KVB 64
__global__ __launch_bounds__(256) void k_attn(
    const bf16* __restrict__ Q,    // [B,H,S,D], pre-scaled by 1/8
    const bf16* __restrict__ Kg,   // [B,H,S,D]
    const bf16* __restrict__ VT,   // [B,H,D,S]
    bf16* __restrict__ O,          // [B,S,H,D]
    float* __restrict__ lossPart) {
    __shared__ bf16 Kl[2][KVB][64];
    __shared__ bf16 Vl[2][D_HEAD][64];
    __shared__ float wred[4];

    const int qb = blockIdx.x;         // 0..31 (64 q-rows per block)
    const int bh = blockIdx.y;         // 0..39
    const int b = bh / H_NUM, hh = bh % H_NUM;
    const int tid = threadIdx.x, lane = tid & 63, wid = tid >> 6;
    const int g = lane >> 4, lr = lane & 15;

    const bf16* Kbase = Kg + (size_t)bh * S_LEN * D_HEAD;
    const bf16* Vbase = VT + (size_t)bh * D_HEAD * S_LEN;

    // per-lane q row
    const int qrow = qb*64 + wid*16 + lr;
    const bf16* qp = Q + ((size_t)bh*S_LEN + qrow)*D_HEAD;
    const bf16x8 aq0 = *(const bf16x8*)(qp + g*8);        // Q^T B-frag, d-half 0
    const bf16x8 aq1 = *(const bf16x8*)(qp + 32 + g*8);   // d-half 1

    // K LDS read-row components (phys kv -> LDS row sigma: swap bits 2,3)
    const int lb7 = (lr & 3) | (((lr >> 2) & 1) << 2);    // LDS row bits 0..2
    const int lhi = ((lr >> 2) & 2) << 3;                 // LDS row bit 4

    f32x4 o_acc[4];
    #pragma unroll
    for (int i=0;i<4;i++) o_acc[i] = zero4();
    float lacc = 0.f, s2acc = 0.f;

#define STAGE(buf, kv0)                                                          \
    {                                                                            \
        _Pragma("unroll")                                                        \
        for (int pp=0; pp<2; ++pp) {                                             \
            int p = pp*256 + tid;                                                \
            int lrow = p >> 3, gp = p & 7;                                       \
            int tl = (lrow & 51) | ((lrow & 4) << 1) | ((lrow & 8) >> 1);        \
            async_copy16((char*)&Kl[buf][0][0] + p*16,                           \
                         Kbase + (size_t)((kv0) + tl)*D_HEAD                     \
                               + ((gp ^ (lrow & 7)) << 3));                      \
        }                                                                        \
        _Pragma("unroll")                                                        \
        for (int pp=0; pp<2; ++pp) {                                             \
            int p = pp*256 + tid;                                                \
            int drow = p >> 3, gp = p & 7;                                       \
            async_copy16((char*)&Vl[buf][0][0] + p*16,                           \
                         Vbase + (size_t)drow*S_LEN + (kv0)                      \
                               + ((gp ^ (drow & 7)) << 3));                      \
        }                                                                        \
    }

    STAGE(0, 0);
    __syncthreads();

    for (int t = 0; t < S_LEN/KVB; ++t) {
        const int cur = t & 1;
        if (t + 1 < S_LEN/KVB) STAGE(cur^1, (t+1)*KVB);
        const bf16* KB = &Kl[cur][0][0];
        const bf16* VB = &Vl[cur][0][0];

        // QK^T (swapped): acc_p[pair][u][r] = S^T[kv = pair*32+g*8+u*4+r][q=qrow]
        f32x4 accp[2][2];
        #pragma unroll
        for (int pair=0; pair<2; ++pair)
            #pragma unroll
            for (int u=0; u<2; ++u) {
                const bf16* kr = KB + (pair*32 + (u<<3) + lhi + lb7)*64;
                bf16x8 k0 = *(const bf16x8*)(kr + ((g       ^ lb7) << 3));
                bf16x8 k1 = *(const bf16x8*)(kr + (((4 + g) ^ lb7) << 3));
                f32x4 c = zero4();
                c = __builtin_amdgcn_mfma_f32_16x16x32_bf16(k0, aq0, c, 0,0,0);
                c = __builtin_amdgcn_mfma_f32_16x16x32_bf16(k1, aq1, c, 0,0,0);
                accp[pair][u] = c;
            }
        // unnormalized p = exp(s): lane-local; pack PV B-fragment in registers
        bf16x8 pb[2];
        #pragma unroll
        for (int pair=0; pair<2; ++pair)
            #pragma unroll
            for (int u=0; u<2; ++u)
                #pragma unroll
                for (int r=0; r<4; ++r) {
                    float e = __expf(accp[pair][u][r]);
                    lacc  += e;
                    s2acc += e*e;
                    pb[pair][u*4+r] = (bf16)e;
                }
        // PV: O^T += V^T . P^T
        #pragma unroll
        for (int ds_=0; ds_<4; ++ds_) {
            const bf16* vr = VB + (ds_*16 + lr)*64;
            #pragma unroll
            for (int pair=0; pair<2; ++pair) {
                bf16x8 v = *(const bf16x8*)(vr + (((pair*4 + g) ^ (lr & 7)) << 3));
                o_acc[ds_] = __builtin_amdgcn_mfma_f32_16x16x32_bf16(v, pb[pair], o_acc[ds_], 0,0,0);
            }
        }
        __syncthreads();   // stage t+1 complete; all waves done with cur
    }

    // reduce l/s2 across the 4 g-groups (lanes differing in bits 4,5)
    float lfull = lacc, s2full = s2acc;
    lfull  += __shfl_xor(lfull, 16);  lfull  += __shfl_xor(lfull, 32);
    s2full += __shfl_xor(s2full, 16); s2full += __shfl_xor(s2full, 32);

    // O write: lane owns q=qrow, holds O^T[d = ds_*16+g*4+r]
    const float inv = 1.0f / lfull;
    bf16* orow = O + ((size_t)(b*S_LEN + qrow)*H_NUM + hh)*D_HEAD;
    #pragma unroll
    for (int ds_=0; ds_<4; ++ds_) {
        bf16x4 ov;
        #pragma unroll
        for (int r=0; r<4; ++r) ov[r] = (bf16)(o_acc[ds_][r] * inv);
        *(bf16x4*)(orow + ds_*16 + g*4) = ov;
    }
    // loss partial: sum over q of s2/l^2 (each q replicated 4x across g -> /4)
    float v = s2full / (lfull*lfull);
    #pragma unroll
    for (int msk=1; msk<64; msk<<=1) v += __shfl_xor(v, msk);
    v *= 0.25f;
    if (lane == 0) wred[wid] = v;
    __syncthreads();
    if (tid == 0) lossPart[bh*32 + qb] = wred[0]+wred[1]+wred[2]+wred[3];
}

// ------------- deterministic loss reduce -------------
__global__ __launch_bounds__(256) void k_loss(const float* __restrict__ part,
                                              float* __restrict__ out, int n) {
    __shared__ float w[4];
    float s = 0.f;
    for (int i = threadIdx.x; i < n; i += 256) s += part[i];
    #pragma unroll
    for (int msk=1; msk<64; msk<<=1) s += __shfl_xor(s, msk);
    int lane = threadIdx.x & 63, wid = threadIdx.x >> 6;
    if (lane==0) w[wid] = s;
    __syncthreads();
    if (threadIdx.x==0) out[(size_t)M_TOT*C_DIM] = sqrtf(w[0]+w[1]+w[2]+w[3]);
}

extern "C" void kernel_launch(void* const* d_in, const int* in_sizes, int n_in,
                              void* d_out, int out_size, void* d_ws, size_t ws_size,
                              hipStream_t stream) {
    (void)in_sizes; (void)n_in; (void)out_size; (void)ws_size;
    const float* hs = (const float*)d_in[0];
    const float* Wq = (const float*)d_in[1];
    const float* Wk = (const float*)d_in[2];
    const float* Wv = (const float*)d_in[3];
    const float* Wo = (const float*)d_in[4];
    const float* bo = (const float*)d_in[5];
    float* out = (float*)d_out;

    constexpr size_t HS_E = (size_t)M_TOT * C_DIM;       // 5,242,880
    constexpr size_t W_E  = (size_t)C_DIM * C_DIM;       // 1,638,400
    char* ws = (char*)d_ws;
    size_t off = 0;
    bf16* hs_bf = (bf16*)(ws + off); off += HS_E * 2;
    bf16* WqT   = (bf16*)(ws + off); off += W_E * 2;
    bf16* WkT   = (bf16*)(ws + off); off += W_E * 2;
    bf16* WvT   = (bf16*)(ws + off); off += W_E * 2;
    bf16* WoT   = (bf16*)(ws + off); off += W_E * 2;
    bf16* Qb    = (bf16*)(ws + off); off += HS_E * 2;
    bf16* Kb    = (bf16*)(ws + off); off += HS_E * 2;
    bf16* Vb    = (bf16*)(ws + off); off += HS_E * 2;
    bf16* Ob    = (bf16*)(ws + off); off += HS_E * 2;
    float* lossPart = (float*)(ws + off); off += 1280 * 4;
    bf16* VTb = hs_bf;   // reuse hs_bf space after QKV GEMMs

    k_convert_hs<<<HS_E/(256*4), 256, 0, stream>>>(hs, hs_bf);
    k_transpose_w<<<dim3(C_DIM/32, C_DIM/32, 4), 256, 0, stream>>>(Wq, Wk, Wv, Wo, WqT, WkT, WvT, WoT);
    k_gemm_qkv<<<dim3(C_DIM/BN, M_TOT/BM, 3), 256, 0, stream>>>(hs_bf, WqT, WkT, WvT, Qb, Kb, Vb);
    k_transpose_v<<<B_SZ*H_NUM*(S_LEN/64), 256, 0, stream>>>(Vb, VTb);
    k_attn<<<dim3(S_LEN/64, B_SZ*H_NUM), 256, 0, stream>>>(Qb, Kb, VTb, Ob, lossPart);
    k_gemm_out<<<dim3(C_DIM/BN, M_TOT/BM), 256, 0, stream>>>(Ob, WoT, bo, hs, out);
    k_loss<<<1, 256, 0, stream>>>(lossPart, out, B_SZ*H_NUM*(S_LEN/64));
}